// Round 15
// baseline (137.389 us; speedup 1.0000x reference)
//
#include <hip/hip_runtime.h>

// Additive attention, factored:
//   scores'[b,q,k] = sum_h (-2 w_h) / (1 + Eq[b,q,h]*Ek[b,k,h]),  Eq=e^{2qp}, Ek=e^{2kp}
// (constant sum_h w_h cancels in softmax). 4-way reciprocal grouping over h.
// Range safety: A..E in [1, ~2e8] -> AB*CE <= ~2e33 < FLT_MAX.
//
// Round-15 (v13): v10 (session best, 131.5us / fused 43.5) restored verbatim;
// ONLY change: phase-1 unroll 2 -> 4 (16 float2 loads in flight per wave).
// Elimination ledger says the score loop's ~30us stall is invariant to traffic,
// occupancy, makespan, line count, and load-instr count; per-wave MLP depth is
// the last untested axis at the best structure. Null result -> declared floor.

#define Bb 8
#define Qn 256
#define Kk 1024
#define Dd 256
#define Hh 128
#define DVv 128

__device__ __forceinline__ float fexp2(float x) { return __builtin_amdgcn_exp2f(x); }
__device__ __forceinline__ float frcp(float x)  { return __builtin_amdgcn_rcpf(x); }

// ---------------------------------------------------------------------------
// K0: W [H][D] -> W4T [D/4][H] float4. 64 blocks x 256 threads.
// ---------------------------------------------------------------------------
__global__ __launch_bounds__(256)
void repack_w(const float* __restrict__ Wq, const float* __restrict__ Wk,
              float4* __restrict__ Wq4T, float4* __restrict__ Wk4T)
{
    const int blk = blockIdx.x;
    const float* src = (blk < 32) ? Wq : Wk;
    float4*      dst = (blk < 32) ? Wq4T : Wk4T;
    const int idx = (blk & 31) * 256 + threadIdx.x;   // 8192 float4 per matrix
    const int g = idx >> 7;          // d-group 0..63
    const int h = idx & 127;
    dst[idx] = *(const float4*)(src + (size_t)h * Dd + g * 4);
}

// ---------------------------------------------------------------------------
// K1: EqT[b][h][r] = exp2(2*log2e * X[r]·W[h]). 640 blocks x 512 threads.
// ---------------------------------------------------------------------------
__global__ __launch_bounds__(512)
void proj_exp_kernel(const float* __restrict__ queries,
                     const float* __restrict__ keys,
                     const float4* __restrict__ Wq4T,
                     const float4* __restrict__ Wk4T,
                     float* __restrict__ EqT,
                     float* __restrict__ EkT)
{
    __shared__ __align__(16) float Xs[16 * 256];     // 16 KB
    const int blk = blockIdx.x;                  // 0..127 queries, 128..639 keys
    const float* X; const float4* W4; float* outT; int RB; int i0;
    if (blk < 128) { X = queries; W4 = Wq4T; outT = EqT; RB = Qn; i0 = blk * 16; }
    else           { X = keys;    W4 = Wk4T; outT = EkT; RB = Kk; i0 = (blk - 128) * 16; }
    const int tid = threadIdx.x;
    const int h   = tid & 127;
    const int r4  = __builtin_amdgcn_readfirstlane(tid >> 7);   // 0..3, wave-uniform

    {   // stage 16x256 X tile, coalesced float4
        const float4* xsrc = (const float4*)(X + (size_t)i0 * Dd);
#pragma unroll
        for (int s = 0; s < 2; ++s) {
            const int idx = tid + 512 * s;       // 1024 float4
            *(float4*)(Xs + idx * 4) = xsrc[idx];
        }
    }
    __syncthreads();

    float acc[4] = {0.f, 0.f, 0.f, 0.f};
    const float4* wp = W4 + h;                   // stride 128 float4 per group
    const float*  xr = Xs + (r4 * 4) * 256;
#pragma unroll 8
    for (int g = 0; g < 64; ++g) {
        const float4 w = wp[(size_t)g * 128];    // coalesced dwordx4
#pragma unroll
        for (int i = 0; i < 4; ++i) {
            const float4 x = *(const float4*)(xr + i * 256 + g * 4);  // broadcast b128
            acc[i] = fmaf(x.x, w.x, acc[i]);
            acc[i] = fmaf(x.y, w.y, acc[i]);
            acc[i] = fmaf(x.z, w.z, acc[i]);
            acc[i] = fmaf(x.w, w.w, acc[i]);
        }
    }
    const int b    = i0 / RB;                    // 16 | RB, never straddles b
    const int rloc = (i0 % RB) + r4 * 4;
    float4 o;
    o.x = fexp2(acc[0] * 2.885390082f);          // e^{2x} = 2^{2x*log2e}
    o.y = fexp2(acc[1] * 2.885390082f);
    o.z = fexp2(acc[2] * 2.885390082f);
    o.w = fexp2(acc[3] * 2.885390082f);
    *(float4*)(outT + (size_t)b * Hh * RB + (size_t)h * RB + rloc) = o;
}

// score update for one (q, k) at 4 h: 14 VALU + 1 rcp
#define SCORE4(q4, w4, ea, eb, ec, ed, accref)                                \
    {                                                                          \
        const float A_ = fmaf((q4).x, (ea), 1.f), B_ = fmaf((q4).y, (eb), 1.f);\
        const float C_ = fmaf((q4).z, (ec), 1.f), E_ = fmaf((q4).w, (ed), 1.f);\
        const float AB_ = A_ * B_, CE_ = C_ * E_;                              \
        const float N_ = fmaf(fmaf((w4).x, B_, (w4).y * A_), CE_,              \
                              fmaf((w4).z, E_, (w4).w * C_) * AB_);            \
        (accref) = fmaf(N_, frcp(AB_ * CE_), (accref));                        \
    }

// ---------------------------------------------------------------------------
// K23 fused v13 (= v10 + unroll 4): grid 512 (qt<<3 | b_raw), 1024 threads.
// Thread (hh = tid>>9, kg = tid&511): ALL 4 q x k pair {2kg, 2kg+1} over its
//   64-h half. Each (h,k) loaded ONCE per block; 64 float2 load-instrs/thread,
//   16 in flight (unroll 4). Merge: hh=0 writes s_sc, barrier, hh=1 adds.
// Wave k-span = 128 k: wave-uniform skip when span >= len.
// Phase 2: softmax, all 16 waves: q = wave&3, quarter = wave>>2.
// Phase 3: P@V, 32 k-slices x 32 v-lanes; 16-wave partial fold via s_part.
// ---------------------------------------------------------------------------
__global__ __launch_bounds__(1024, 4)
void score_softmax_pv_kernel(const float* __restrict__ EqT,
                             const float* __restrict__ EkT,
                             const float* __restrict__ wv,
                             const int* __restrict__ valid_lens,
                             const float* __restrict__ values,
                             float* __restrict__ out)
{
    __shared__ __align__(16) float  s_sc[4][Kk];        // 16 KB
    __shared__ __align__(16) float  eqsT[4][Hh];        // 2 KB  [q][h]
    __shared__ __align__(16) float  w2s[Hh];            // 0.5 KB
    __shared__ __align__(16) float4 s_part[15][4][32];  // 30 KB
    __shared__ float s_qmax[4][4];
    __shared__ float s_qsum[4][4];

    const int blk  = blockIdx.x;
    const int qt   = blk >> 3;                    // 0..63
    const int b    = (blk & 7) ^ ((qt & 32) ? 4 : 0);   // co-resident blocks: diff b
    const int q0   = qt * 4;
    const int len  = valid_lens[b];
    const int tid  = threadIdx.x;
    const int lane = tid & 63;
    const int wave = __builtin_amdgcn_readfirstlane(tid >> 6);   // 0..15

    // ---- stage eqT (transposed: [q][h]) and -2*wv
    if (tid < 128) {
        const float4 v = *(const float4*)(EqT + (size_t)b * Hh * Qn + (size_t)tid * Qn + q0);
        eqsT[0][tid] = v.x; eqsT[1][tid] = v.y; eqsT[2][tid] = v.z; eqsT[3][tid] = v.w;
    } else if (tid < 256) {
        w2s[tid - 128] = -2.0f * wv[tid - 128];
    }
    __syncthreads();

    const int hh = __builtin_amdgcn_readfirstlane(tid >> 9);     // 0..1: h-half
    const int kg = tid & 511;                                    // k-pair index
    const int kspan = ((tid >> 6) & 7) << 7;                     // wave's 128-k base
    const bool live = (kspan < len);              // wave-uniform (tail never read)

    // ---- phase 1: partial scores for 4 q x 2 k over this thread's 64 h
    float acc[4][2] = {};
    if (live) {
        const float2* ek2 = (const float2*)(EkT + (size_t)b * Hh * Kk) + kg;
        const int h0 = hh << 6;                   // 0 or 64
#pragma unroll 4
        for (int hg = 0; hg < 16; ++hg) {
            const int h = h0 + (hg << 2);
            const float2 e0 = ek2[(size_t)(h + 0) * (Kk / 2)];   // dwordx2, coalesced
            const float2 e1 = ek2[(size_t)(h + 1) * (Kk / 2)];
            const float2 e2 = ek2[(size_t)(h + 2) * (Kk / 2)];
            const float2 e3 = ek2[(size_t)(h + 3) * (Kk / 2)];
            const float4 w4 = *(const float4*)(w2s + h);         // LDS broadcast b128
#pragma unroll
            for (int q = 0; q < 4; ++q) {
                const float4 q4 = *(const float4*)(&eqsT[q][h]);
                SCORE4(q4, w4, e0.x, e1.x, e2.x, e3.x, acc[q][0]);
                SCORE4(q4, w4, e0.y, e1.y, e2.y, e3.y, acc[q][1]);
            }
        }
    }
    // merge h-halves: hh=0 writes, barrier, hh=1 read-add-writes
    if (hh == 0 && live) {
#pragma unroll
        for (int q = 0; q < 4; ++q)               // b64, 2 lanes/bank: free
            *(float2*)(&s_sc[q][kg << 1]) = make_float2(acc[q][0], acc[q][1]);
    }
    __syncthreads();
    if (hh == 1 && live) {
#pragma unroll
        for (int q = 0; q < 4; ++q) {
            float2 p = *(const float2*)(&s_sc[q][kg << 1]);
            p.x += acc[q][0]; p.y += acc[q][1];
            *(float2*)(&s_sc[q][kg << 1]) = p;
        }
    }
    __syncthreads();

    // ---- phase 2: masked softmax, all 16 waves: q = wave&3, quarter = wave>>2
    {
        const int q    = wave & 3;
        const int qtr  = wave >> 2;
        const int base = qtr * 256;
        const int hi   = (base + 256 < len) ? base + 256 : len;
        float m = -3.0e38f;
        for (int i = base + lane; i < hi; i += 64) m = fmaxf(m, s_sc[q][i]);
#pragma unroll
        for (int off = 32; off > 0; off >>= 1) m = fmaxf(m, __shfl_xor(m, off));
        if (lane == 0) s_qmax[q][qtr] = m;
        __syncthreads();
        const float gm = fmaxf(fmaxf(s_qmax[q][0], s_qmax[q][1]),
                               fmaxf(s_qmax[q][2], s_qmax[q][3]));
        float sum = 0.f;
        for (int i = base + lane; i < hi; i += 64) {
            const float p = fexp2((s_sc[q][i] - gm) * 1.44269504f);
            s_sc[q][i] = p;
            sum += p;
        }
#pragma unroll
        for (int off = 32; off > 0; off >>= 1) sum += __shfl_xor(sum, off);
        if (lane == 0) s_qsum[q][qtr] = sum;
    }
    __syncthreads();

    // ---- phase 3: P@V, 32 k-slices x (32 lanes x float4 = 128 v)
    {
        const int slice = tid >> 5;               // 0..31
        const int l32   = tid & 31;
        const int v4    = l32 << 2;
        const float* vp = values + (size_t)b * Kk * DVv + v4;
        float a[4][4];
#pragma unroll
        for (int q = 0; q < 4; ++q) { a[q][0]=0.f; a[q][1]=0.f; a[q][2]=0.f; a[q][3]=0.f; }
        for (int k = slice; k < len; k += 32) {
            const float4 val = *(const float4*)(vp + (size_t)k * DVv);
            const float w0 = s_sc[0][k], w1 = s_sc[1][k], w2 = s_sc[2][k], w3 = s_sc[3][k];
            a[0][0] = fmaf(w0, val.x, a[0][0]);
            a[0][1] = fmaf(w0, val.y, a[0][1]);
            a[0][2] = fmaf(w0, val.z, a[0][2]);
            a[0][3] = fmaf(w0, val.w, a[0][3]);
            a[1][0] = fmaf(w1, val.x, a[1][0]);
            a[1][1] = fmaf(w1, val.y, a[1][1]);
            a[1][2] = fmaf(w1, val.z, a[1][2]);
            a[1][3] = fmaf(w1, val.w, a[1][3]);
            a[2][0] = fmaf(w2, val.x, a[2][0]);
            a[2][1] = fmaf(w2, val.y, a[2][1]);
            a[2][2] = fmaf(w2, val.z, a[2][2]);
            a[2][3] = fmaf(w2, val.w, a[2][3]);
            a[3][0] = fmaf(w3, val.x, a[3][0]);
            a[3][1] = fmaf(w3, val.y, a[3][1]);
            a[3][2] = fmaf(w3, val.z, a[3][2]);
            a[3][3] = fmaf(w3, val.w, a[3][3]);
        }
        // fold the two slices within each wave (slice 2w | 2w+1)
#pragma unroll
        for (int q = 0; q < 4; ++q)
#pragma unroll
            for (int x = 0; x < 4; ++x) a[q][x] += __shfl_xor(a[q][x], 32);
        if (wave > 0 && lane < 32) {
#pragma unroll
            for (int q = 0; q < 4; ++q)
                s_part[wave - 1][q][l32] = make_float4(a[q][0], a[q][1], a[q][2], a[q][3]);
        }
        __syncthreads();
        if (wave == 0 && lane < 32) {
#pragma unroll
            for (int q = 0; q < 4; ++q) {
                float r0 = a[q][0], r1 = a[q][1], r2 = a[q][2], r3 = a[q][3];
#pragma unroll
                for (int w = 0; w < 15; ++w) {
                    const float4 p = s_part[w][q][l32];
                    r0 += p.x; r1 += p.y; r2 += p.z; r3 += p.w;
                }
                const float inv = frcp(s_qsum[q][0] + s_qsum[q][1] +
                                       s_qsum[q][2] + s_qsum[q][3]);
                *(float4*)(out + (size_t)(b * Qn + q0 + q) * DVv + v4) =
                    make_float4(r0 * inv, r1 * inv, r2 * inv, r3 * inv);
            }
        }
    }
}

extern "C" void kernel_launch(void* const* d_in, const int* in_sizes, int n_in,
                              void* d_out, int out_size, void* d_ws, size_t ws_size,
                              hipStream_t stream) {
    (void)in_sizes; (void)n_in; (void)out_size; (void)ws_size;
    const float* queries    = (const float*)d_in[0];
    const float* keys       = (const float*)d_in[1];
    const float* values     = (const float*)d_in[2];
    const int*   valid_lens = (const int*)  d_in[3];
    const float* Wq         = (const float*)d_in[4];
    const float* Wk         = (const float*)d_in[5];
    const float* wvv        = (const float*)d_in[6];
    float* out = (float*)d_out;

    float* Wq4T = (float*)d_ws;                                  // 256*128 floats
    float* Wk4T = Wq4T + (size_t)Dd * Hh;
    float* EqT  = Wk4T + (size_t)Dd * Hh;                        // 8*128*256
    float* EkT  = EqT + (size_t)Bb * Hh * Qn;                    // 8*128*1024

    repack_w       <<<  64, 256, 0, stream>>>(Wq, Wk, (float4*)Wq4T, (float4*)Wk4T);
    proj_exp_kernel<<< 640, 512, 0, stream>>>(queries, keys, (const float4*)Wq4T,
                                              (const float4*)Wk4T, EqT, EkT);
    score_softmax_pv_kernel<<<512, 1024, 0, stream>>>(EqT, EkT, wvv, valid_lens,
                                                      values, out);
}

// Round 16
// 130.330 us; speedup vs baseline: 1.0542x; 1.0542x over previous
//
#include <hip/hip_runtime.h>

// Additive attention, factored:
//   scores'[b,q,k] = sum_h (-2 w_h) / (1 + Eq[b,q,h]*Ek[b,k,h]),  Eq=e^{2qp}, Ek=e^{2kp}
// (constant sum_h w_h cancels in softmax). 4-way reciprocal grouping over h.
// Range safety: A..E in [1, ~2e8] -> AB*CE <= ~2e33 < FLT_MAX.
//
// FINAL (v10, session best 131.5us): each (h,k) loaded once per block via the
// two qh-groups splitting H (64 float2 loads/thread); merge via plain LDS
// write->barrier->add. Score loop measured at its latency floor (~43us ~=
// 3.3x VALU-issue floor) -- invariant across 13 structural variants spanning
// traffic (670->170MB), occupancy (22-62%), loads/thread (128/64/32), payload
// (4-16B), split/fused, equal-item backfill, LDS pipelining, per-CU line
// count, merge scheme, and unroll depth. Remaining dur_us is dominated by
// harness workspace re-poison fills (~6.3TB/s, immovable from kernel side).

#define Bb 8
#define Qn 256
#define Kk 1024
#define Dd 256
#define Hh 128
#define DVv 128

__device__ __forceinline__ float fexp2(float x) { return __builtin_amdgcn_exp2f(x); }
__device__ __forceinline__ float frcp(float x)  { return __builtin_amdgcn_rcpf(x); }

// ---------------------------------------------------------------------------
// K0: W [H][D] -> W4T [D/4][H] float4. 64 blocks x 256 threads.
// ---------------------------------------------------------------------------
__global__ __launch_bounds__(256)
void repack_w(const float* __restrict__ Wq, const float* __restrict__ Wk,
              float4* __restrict__ Wq4T, float4* __restrict__ Wk4T)
{
    const int blk = blockIdx.x;
    const float* src = (blk < 32) ? Wq : Wk;
    float4*      dst = (blk < 32) ? Wq4T : Wk4T;
    const int idx = (blk & 31) * 256 + threadIdx.x;   // 8192 float4 per matrix
    const int g = idx >> 7;          // d-group 0..63
    const int h = idx & 127;
    dst[idx] = *(const float4*)(src + (size_t)h * Dd + g * 4);
}

// ---------------------------------------------------------------------------
// K1: EqT[b][h][r] = exp2(2*log2e * X[r]·W[h]). 640 blocks x 512 threads.
// ---------------------------------------------------------------------------
__global__ __launch_bounds__(512)
void proj_exp_kernel(const float* __restrict__ queries,
                     const float* __restrict__ keys,
                     const float4* __restrict__ Wq4T,
                     const float4* __restrict__ Wk4T,
                     float* __restrict__ EqT,
                     float* __restrict__ EkT)
{
    __shared__ __align__(16) float Xs[16 * 256];     // 16 KB
    const int blk = blockIdx.x;                  // 0..127 queries, 128..639 keys
    const float* X; const float4* W4; float* outT; int RB; int i0;
    if (blk < 128) { X = queries; W4 = Wq4T; outT = EqT; RB = Qn; i0 = blk * 16; }
    else           { X = keys;    W4 = Wk4T; outT = EkT; RB = Kk; i0 = (blk - 128) * 16; }
    const int tid = threadIdx.x;
    const int h   = tid & 127;
    const int r4  = __builtin_amdgcn_readfirstlane(tid >> 7);   // 0..3, wave-uniform

    {   // stage 16x256 X tile, coalesced float4
        const float4* xsrc = (const float4*)(X + (size_t)i0 * Dd);
#pragma unroll
        for (int s = 0; s < 2; ++s) {
            const int idx = tid + 512 * s;       // 1024 float4
            *(float4*)(Xs + idx * 4) = xsrc[idx];
        }
    }
    __syncthreads();

    float acc[4] = {0.f, 0.f, 0.f, 0.f};
    const float4* wp = W4 + h;                   // stride 128 float4 per group
    const float*  xr = Xs + (r4 * 4) * 256;
#pragma unroll 8
    for (int g = 0; g < 64; ++g) {
        const float4 w = wp[(size_t)g * 128];    // coalesced dwordx4
#pragma unroll
        for (int i = 0; i < 4; ++i) {
            const float4 x = *(const float4*)(xr + i * 256 + g * 4);  // broadcast b128
            acc[i] = fmaf(x.x, w.x, acc[i]);
            acc[i] = fmaf(x.y, w.y, acc[i]);
            acc[i] = fmaf(x.z, w.z, acc[i]);
            acc[i] = fmaf(x.w, w.w, acc[i]);
        }
    }
    const int b    = i0 / RB;                    // 16 | RB, never straddles b
    const int rloc = (i0 % RB) + r4 * 4;
    float4 o;
    o.x = fexp2(acc[0] * 2.885390082f);          // e^{2x} = 2^{2x*log2e}
    o.y = fexp2(acc[1] * 2.885390082f);
    o.z = fexp2(acc[2] * 2.885390082f);
    o.w = fexp2(acc[3] * 2.885390082f);
    *(float4*)(outT + (size_t)b * Hh * RB + (size_t)h * RB + rloc) = o;
}

// score update for one (q, k) at 4 h: 14 VALU + 1 rcp
#define SCORE4(q4, w4, ea, eb, ec, ed, accref)                                \
    {                                                                          \
        const float A_ = fmaf((q4).x, (ea), 1.f), B_ = fmaf((q4).y, (eb), 1.f);\
        const float C_ = fmaf((q4).z, (ec), 1.f), E_ = fmaf((q4).w, (ed), 1.f);\
        const float AB_ = A_ * B_, CE_ = C_ * E_;                              \
        const float N_ = fmaf(fmaf((w4).x, B_, (w4).y * A_), CE_,              \
                              fmaf((w4).z, E_, (w4).w * C_) * AB_);            \
        (accref) = fmaf(N_, frcp(AB_ * CE_), (accref));                        \
    }

// ---------------------------------------------------------------------------
// K23 fused v10: grid 512 (qt<<3 | b_raw), 1024 threads (16 waves).
// Thread (hh = tid>>9, kg = tid&511): ALL 4 q x k pair {2kg, 2kg+1} over its
//   64-h half (h in [64*hh, 64*hh+64)). Each (h,k) loaded ONCE per block;
//   64 float2 load-instrs per thread. Merge: hh=0 writes s_sc,
//   barrier, hh=1 read-add-writes (plain LDS, b64, conflict-free).
// Wave k-span = 128 k: wave-uniform skip when span >= len.
// Phase 2: softmax, all 16 waves: q = wave&3, quarter = wave>>2.
// Phase 3: P@V, 32 k-slices x 32 v-lanes; 16-wave partial fold via s_part.
// ---------------------------------------------------------------------------
__global__ __launch_bounds__(1024, 4)
void score_softmax_pv_kernel(const float* __restrict__ EqT,
                             const float* __restrict__ EkT,
                             const float* __restrict__ wv,
                             const int* __restrict__ valid_lens,
                             const float* __restrict__ values,
                             float* __restrict__ out)
{
    __shared__ __align__(16) float  s_sc[4][Kk];        // 16 KB
    __shared__ __align__(16) float  eqsT[4][Hh];        // 2 KB  [q][h]
    __shared__ __align__(16) float  w2s[Hh];            // 0.5 KB
    __shared__ __align__(16) float4 s_part[15][4][32];  // 30 KB
    __shared__ float s_qmax[4][4];
    __shared__ float s_qsum[4][4];

    const int blk  = blockIdx.x;
    const int qt   = blk >> 3;                    // 0..63
    const int b    = (blk & 7) ^ ((qt & 32) ? 4 : 0);   // co-resident blocks: diff b
    const int q0   = qt * 4;
    const int len  = valid_lens[b];
    const int tid  = threadIdx.x;
    const int lane = tid & 63;
    const int wave = __builtin_amdgcn_readfirstlane(tid >> 6);   // 0..15

    // ---- stage eqT (transposed: [q][h]) and -2*wv
    if (tid < 128) {
        const float4 v = *(const float4*)(EqT + (size_t)b * Hh * Qn + (size_t)tid * Qn + q0);
        eqsT[0][tid] = v.x; eqsT[1][tid] = v.y; eqsT[2][tid] = v.z; eqsT[3][tid] = v.w;
    } else if (tid < 256) {
        w2s[tid - 128] = -2.0f * wv[tid - 128];
    }
    __syncthreads();

    const int hh = __builtin_amdgcn_readfirstlane(tid >> 9);     // 0..1: h-half
    const int kg = tid & 511;                                    // k-pair index
    const int kspan = ((tid >> 6) & 7) << 7;                     // wave's 128-k base
    const bool live = (kspan < len);              // wave-uniform (tail never read)

    // ---- phase 1: partial scores for 4 q x 2 k over this thread's 64 h
    float acc[4][2] = {};
    if (live) {
        const float2* ek2 = (const float2*)(EkT + (size_t)b * Hh * Kk) + kg;
        const int h0 = hh << 6;                   // 0 or 64
#pragma unroll 2
        for (int hg = 0; hg < 16; ++hg) {
            const int h = h0 + (hg << 2);
            const float2 e0 = ek2[(size_t)(h + 0) * (Kk / 2)];   // dwordx2, coalesced
            const float2 e1 = ek2[(size_t)(h + 1) * (Kk / 2)];
            const float2 e2 = ek2[(size_t)(h + 2) * (Kk / 2)];
            const float2 e3 = ek2[(size_t)(h + 3) * (Kk / 2)];
            const float4 w4 = *(const float4*)(w2s + h);         // LDS broadcast b128
#pragma unroll
            for (int q = 0; q < 4; ++q) {
                const float4 q4 = *(const float4*)(&eqsT[q][h]);
                SCORE4(q4, w4, e0.x, e1.x, e2.x, e3.x, acc[q][0]);
                SCORE4(q4, w4, e0.y, e1.y, e2.y, e3.y, acc[q][1]);
            }
        }
    }
    // merge h-halves: hh=0 writes, barrier, hh=1 read-add-writes
    if (hh == 0 && live) {
#pragma unroll
        for (int q = 0; q < 4; ++q)               // b64, 2 lanes/bank: free
            *(float2*)(&s_sc[q][kg << 1]) = make_float2(acc[q][0], acc[q][1]);
    }
    __syncthreads();
    if (hh == 1 && live) {
#pragma unroll
        for (int q = 0; q < 4; ++q) {
            float2 p = *(const float2*)(&s_sc[q][kg << 1]);
            p.x += acc[q][0]; p.y += acc[q][1];
            *(float2*)(&s_sc[q][kg << 1]) = p;
        }
    }
    __syncthreads();

    // ---- phase 2: masked softmax, all 16 waves: q = wave&3, quarter = wave>>2
    {
        const int q    = wave & 3;
        const int qtr  = wave >> 2;
        const int base = qtr * 256;
        const int hi   = (base + 256 < len) ? base + 256 : len;
        float m = -3.0e38f;
        for (int i = base + lane; i < hi; i += 64) m = fmaxf(m, s_sc[q][i]);
#pragma unroll
        for (int off = 32; off > 0; off >>= 1) m = fmaxf(m, __shfl_xor(m, off));
        if (lane == 0) s_qmax[q][qtr] = m;
        __syncthreads();
        const float gm = fmaxf(fmaxf(s_qmax[q][0], s_qmax[q][1]),
                               fmaxf(s_qmax[q][2], s_qmax[q][3]));
        float sum = 0.f;
        for (int i = base + lane; i < hi; i += 64) {
            const float p = fexp2((s_sc[q][i] - gm) * 1.44269504f);
            s_sc[q][i] = p;
            sum += p;
        }
#pragma unroll
        for (int off = 32; off > 0; off >>= 1) sum += __shfl_xor(sum, off);
        if (lane == 0) s_qsum[q][qtr] = sum;
    }
    __syncthreads();

    // ---- phase 3: P@V, 32 k-slices x (32 lanes x float4 = 128 v)
    {
        const int slice = tid >> 5;               // 0..31
        const int l32   = tid & 31;
        const int v4    = l32 << 2;
        const float* vp = values + (size_t)b * Kk * DVv + v4;
        float a[4][4];
#pragma unroll
        for (int q = 0; q < 4; ++q) { a[q][0]=0.f; a[q][1]=0.f; a[q][2]=0.f; a[q][3]=0.f; }
        for (int k = slice; k < len; k += 32) {
            const float4 val = *(const float4*)(vp + (size_t)k * DVv);
            const float w0 = s_sc[0][k], w1 = s_sc[1][k], w2 = s_sc[2][k], w3 = s_sc[3][k];
            a[0][0] = fmaf(w0, val.x, a[0][0]);
            a[0][1] = fmaf(w0, val.y, a[0][1]);
            a[0][2] = fmaf(w0, val.z, a[0][2]);
            a[0][3] = fmaf(w0, val.w, a[0][3]);
            a[1][0] = fmaf(w1, val.x, a[1][0]);
            a[1][1] = fmaf(w1, val.y, a[1][1]);
            a[1][2] = fmaf(w1, val.z, a[1][2]);
            a[1][3] = fmaf(w1, val.w, a[1][3]);
            a[2][0] = fmaf(w2, val.x, a[2][0]);
            a[2][1] = fmaf(w2, val.y, a[2][1]);
            a[2][2] = fmaf(w2, val.z, a[2][2]);
            a[2][3] = fmaf(w2, val.w, a[2][3]);
            a[3][0] = fmaf(w3, val.x, a[3][0]);
            a[3][1] = fmaf(w3, val.y, a[3][1]);
            a[3][2] = fmaf(w3, val.z, a[3][2]);
            a[3][3] = fmaf(w3, val.w, a[3][3]);
        }
        // fold the two slices within each wave (slice 2w | 2w+1)
#pragma unroll
        for (int q = 0; q < 4; ++q)
#pragma unroll
            for (int x = 0; x < 4; ++x) a[q][x] += __shfl_xor(a[q][x], 32);
        if (wave > 0 && lane < 32) {
#pragma unroll
            for (int q = 0; q < 4; ++q)
                s_part[wave - 1][q][l32] = make_float4(a[q][0], a[q][1], a[q][2], a[q][3]);
        }
        __syncthreads();
        if (wave == 0 && lane < 32) {
#pragma unroll
            for (int q = 0; q < 4; ++q) {
                float r0 = a[q][0], r1 = a[q][1], r2 = a[q][2], r3 = a[q][3];
#pragma unroll
                for (int w = 0; w < 15; ++w) {
                    const float4 p = s_part[w][q][l32];
                    r0 += p.x; r1 += p.y; r2 += p.z; r3 += p.w;
                }
                const float inv = frcp(s_qsum[q][0] + s_qsum[q][1] +
                                       s_qsum[q][2] + s_qsum[q][3]);
                *(float4*)(out + (size_t)(b * Qn + q0 + q) * DVv + v4) =
                    make_float4(r0 * inv, r1 * inv, r2 * inv, r3 * inv);
            }
        }
    }
}

extern "C" void kernel_launch(void* const* d_in, const int* in_sizes, int n_in,
                              void* d_out, int out_size, void* d_ws, size_t ws_size,
                              hipStream_t stream) {
    (void)in_sizes; (void)n_in; (void)out_size; (void)ws_size;
    const float* queries    = (const float*)d_in[0];
    const float* keys       = (const float*)d_in[1];
    const float* values     = (const float*)d_in[2];
    const int*   valid_lens = (const int*)  d_in[3];
    const float* Wq         = (const float*)d_in[4];
    const float* Wk         = (const float*)d_in[5];
    const float* wvv        = (const float*)d_in[6];
    float* out = (float*)d_out;

    float* Wq4T = (float*)d_ws;                                  // 256*128 floats
    float* Wk4T = Wq4T + (size_t)Dd * Hh;
    float* EqT  = Wk4T + (size_t)Dd * Hh;                        // 8*128*256
    float* EkT  = EqT + (size_t)Bb * Hh * Qn;                    // 8*128*1024

    repack_w       <<<  64, 256, 0, stream>>>(Wq, Wk, (float4*)Wq4T, (float4*)Wk4T);
    proj_exp_kernel<<< 640, 512, 0, stream>>>(queries, keys, (const float4*)Wq4T,
                                              (const float4*)Wk4T, EqT, EkT);
    score_softmax_pv_kernel<<<512, 1024, 0, stream>>>(EqT, EkT, wvv, valid_lens,
                                                      values, out);
}